// Round 4
// baseline (280.892 us; speedup 1.0000x reference)
//
#include <hip/hip_runtime.h>

#define N0 6400
#define NC 256
#define WW 80

using half8   = __attribute__((ext_vector_type(8))) _Float16;
using floatx4 = __attribute__((ext_vector_type(4))) float;
#define GLOBAL_AS __attribute__((address_space(1)))
#define LDS_AS    __attribute__((address_space(3)))

__device__ __forceinline__ unsigned long long packvi(float v, int i) {
    return ((unsigned long long)__float_as_uint(v) << 32) | (unsigned int)i;
}

// ---------------- K1: partial sumsq over channel halves + zero-inits ----
// grid 100: g in [0,25600); h = channel half, j = column id (f0: 0..6399,
// f1: 6400..12799). Pure writes to snorm[h*12800+j] -> no init needed.
__global__ __launch_bounds__(256) void knorm(const float* __restrict__ f0,
                                             const float* __restrict__ f1,
                                             float* __restrict__ snorm,
                                             float* __restrict__ rowsum,
                                             float* __restrict__ colsum,
                                             unsigned long long* __restrict__ rowbest,
                                             unsigned long long* __restrict__ colbest) {
    int g = blockIdx.x * 256 + threadIdx.x;          // 0..25599
    if (g < N0) {                                    // zero reduction buffers
        rowsum[g] = 0.f; colsum[g] = 0.f;
        rowbest[g] = 0ull; colbest[g] = 0ull;
    }
    int h = (g >= 12800) ? 1 : 0;
    int j = g - h * 12800;                           // 0..12799
    const float* src = (j < N0) ? f0 : f1;
    int n = (j < N0) ? j : (j - N0);
    int c0 = h * 128;
    float s = 0.f;
#pragma unroll 8
    for (int c = 0; c < 128; ++c) {
        float v = src[(c0 + c) * N0 + n];
        s += v * v;
    }
    snorm[g] = s;
}

// -------- K2: transpose (C,N)->(N,256) fp16, normalized; z selects f0/f1
__global__ __launch_bounds__(256) void ktrans(const float* __restrict__ f0,
                                              const float* __restrict__ f1,
                                              const float* __restrict__ snorm,
                                              _Float16* __restrict__ A2,
                                              _Float16* __restrict__ B2) {
    __shared__ float tile[32][33];
    const float* src = blockIdx.z ? f1 : f0;
    _Float16* dst    = blockIdx.z ? B2 : A2;
    int t = threadIdx.x;
    int n0 = blockIdx.x * 32, c0 = blockIdx.y * 32;
    int tx = t & 31, ty = t >> 5;                    // 32 x 8
#pragma unroll
    for (int u = 0; u < 4; ++u)
        tile[ty + u * 8][tx] = src[(c0 + ty + u * 8) * N0 + n0 + tx];
    __syncthreads();
    int row = t >> 3;            // 0..31 (local n)
    int cg  = (t & 7) * 4;       // 0..28 (local c, groups of 4)
    int n = n0 + row;
    int j = (blockIdx.z ? N0 : 0) + n;
    float s = snorm[j] + snorm[12800 + j];
    float iv = 1.0f / fmaxf(sqrtf(s), 1e-12f);
    union { ushort4 u4; _Float16 h[4]; } pk;
#pragma unroll
    for (int u = 0; u < 4; ++u)
        pk.h[u] = (_Float16)(tile[cg + u][row] * iv);
    *(ushort4*)&dst[n * NC + c0 + cg] = pk.u4;
}

// ---------------- staging: 128 rows x 128 k-values (half-K chunk) -------
// Chunk layout: [kk2(2)][row(128)][64 halves] = 16384 ushorts (32 KiB).
// 16B chunk placed at (chunk ^ (row&7)) — swizzle on the GLOBAL source so
// the LDS destination stays lane-linear (global_load_lds requirement).
__device__ __forceinline__ void stage_chunk(const _Float16* __restrict__ G,
                                            unsigned short* lds, int r0, int kc,
                                            int tid) {
    int rl = tid >> 3;                               // 0..31
    int ch = ((tid & 7) ^ (rl & 7)) * 8;             // swizzled chunk (halves)
#pragma unroll
    for (int kk = 0; kk < 2; ++kk)
#pragma unroll
        for (int g = 0; g < 4; ++g) {
            const _Float16* ga = G + (r0 + g * 32 + rl) * NC + kc * 128 + kk * 64 + ch;
            __builtin_amdgcn_global_load_lds((const GLOBAL_AS unsigned int*)ga,
                (LDS_AS unsigned int*)&lds[kk * 8192 + g * 2048 + tid * 8], 16, 0, 0);
        }
}

// ---------------- half-K compute: 4 s-steps, 64 MFMA/wave ---------------
// LO: A fragments from registers. HI: A fragments from persistent LDS.
template<bool HI>
__device__ __forceinline__ void compute_half(const unsigned short* bbuf,
                                             const unsigned short* abufHi,
                                             const half8 aflo[4][4],
                                             int lane, int wm, int wn,
                                             floatx4 acc[4][4]) {
    int q = lane >> 4;
#pragma unroll
    for (int s = 0; s < 4; ++s) {
        int c = s * 4 + q, kk = c >> 3, cq = c & 7;
        half8 af[4], bf[4];
#pragma unroll
        for (int mt = 0; mt < 4; ++mt) {
            int rb = wn * 64 + mt * 16 + (lane & 15);
            bf[mt] = *(const half8*)&bbuf[kk * 8192 + rb * 64 + ((cq ^ (rb & 7)) * 8)];
        }
#pragma unroll
        for (int mt = 0; mt < 4; ++mt) {
            if (HI) {
                int ra = wm * 64 + mt * 16 + (lane & 15);
                af[mt] = *(const half8*)&abufHi[kk * 8192 + ra * 64 + ((cq ^ (ra & 7)) * 8)];
            } else {
                af[mt] = aflo[mt][s];
            }
        }
#pragma unroll
        for (int mt = 0; mt < 4; ++mt)
#pragma unroll
            for (int nt = 0; nt < 4; ++nt)
                acc[mt][nt] = __builtin_amdgcn_mfma_f32_16x16x32_f16(
                    af[mt], bf[nt], acc[mt][nt], 0, 0, 0);
    }
}

// ---------------- K3: GEMM pass 1 — row/col sums of exp(S) --------------
// Grid (50,10) = 500 blocks, 2 blocks/CU (64 KiB LDS, <=256 VGPR): TLP
// hides stage latency and the exp/reduce VALU tail under the sibling
// block's MFMAs. Block = 128-row A panel x 640-col B stripe (5 j-tiles).
__global__ __launch_bounds__(256, 2) void kgemm1(const _Float16* __restrict__ A2,
                                                 const _Float16* __restrict__ B2,
                                                 float* __restrict__ rowsum,
                                                 float* __restrict__ colsum) {
    __shared__ __align__(16) unsigned short lds[32768];   // 64 KiB
    unsigned short* regA = lds;                           // A k-high, persistent
    unsigned short* regB = lds + 16384;                   // B staging buffer
    int tid = threadIdx.x, lane = tid & 63, wave = tid >> 6;
    int wm = wave & 1, wn = wave >> 1, q = lane >> 4;
    int i0 = blockIdx.x * 128, jp = blockIdx.y * 640;

    stage_chunk(A2, regB, i0, 0, tid);               // A k-low (transient)
    stage_chunk(A2, regA, i0, 1, tid);               // A k-high (persistent)
    __syncthreads();
    half8 aflo[4][4];                                // A k-low fragments -> regs
#pragma unroll
    for (int mt = 0; mt < 4; ++mt)
#pragma unroll
        for (int s = 0; s < 4; ++s) {
            int c = s * 4 + q, kk = c >> 3, cq = c & 7;
            int ra = wm * 64 + mt * 16 + (lane & 15);
            aflo[mt][s] = *(const half8*)&regB[kk * 8192 + ra * 64 + ((cq ^ (ra & 7)) * 8)];
        }
    __syncthreads();                                 // regB free

    float rsum[4][4] = {};

    for (int jt = 0; jt < 5; ++jt) {
        stage_chunk(B2, regB, jp + jt * 128, 0, tid);
        __syncthreads();
        floatx4 acc[4][4] = {};
        compute_half<false>(regB, regA, aflo, lane, wm, wn, acc);
        __syncthreads();
        stage_chunk(B2, regB, jp + jt * 128, 1, tid);
        __syncthreads();
        compute_half<true>(regB, regA, aflo, lane, wm, wn, acc);

        float csum[4] = {0.f, 0.f, 0.f, 0.f};
#pragma unroll
        for (int mt = 0; mt < 4; ++mt)
#pragma unroll
            for (int r = 0; r < 4; ++r) {
                float rv = 0.f;
#pragma unroll
                for (int nt = 0; nt < 4; ++nt) {
                    float e = __expf(10.0f * acc[mt][nt][r]);
                    rv += e; csum[nt] += e;
                }
                rsum[mt][r] += rv;
            }
#pragma unroll
        for (int nt = 0; nt < 4; ++nt) {
            csum[nt] += __shfl_xor(csum[nt], 16);
            csum[nt] += __shfl_xor(csum[nt], 32);
        }
        if (lane < 16)
#pragma unroll
            for (int nt = 0; nt < 4; ++nt)
                atomicAdd(&colsum[jp + jt * 128 + wn * 64 + nt * 16 + lane], csum[nt]);
        __syncthreads();                             // regB reads done
    }
#pragma unroll
    for (int mt = 0; mt < 4; ++mt)
#pragma unroll
        for (int r = 0; r < 4; ++r) {
            float v = rsum[mt][r];
            v += __shfl_xor(v, 1);
            v += __shfl_xor(v, 2);
            v += __shfl_xor(v, 4);
            v += __shfl_xor(v, 8);
            if ((lane & 15) == 0)
                atomicAdd(&rowsum[i0 + wm * 64 + mt * 16 + q * 4 + r], v);
        }
}

// ---------------- K4: GEMM pass 2 — P writes + fused argmax -------------
__global__ __launch_bounds__(256, 2) void kgemm2(const _Float16* __restrict__ A2,
                                                 const _Float16* __restrict__ B2,
                                                 const float* __restrict__ rowsum,
                                                 const float* __restrict__ colsum,
                                                 float* __restrict__ P,
                                                 unsigned long long* __restrict__ rowbest,
                                                 unsigned long long* __restrict__ colbest) {
    __shared__ __align__(16) unsigned short lds[32768];   // 64 KiB
    unsigned short* regA = lds;
    unsigned short* regB = lds + 16384;
    int tid = threadIdx.x, lane = tid & 63, wave = tid >> 6;
    int wm = wave & 1, wn = wave >> 1, q = lane >> 4;
    int i0 = blockIdx.x * 128, jp = blockIdx.y * 640;

    stage_chunk(A2, regB, i0, 0, tid);
    stage_chunk(A2, regA, i0, 1, tid);
    __syncthreads();
    half8 aflo[4][4];
#pragma unroll
    for (int mt = 0; mt < 4; ++mt)
#pragma unroll
        for (int s = 0; s < 4; ++s) {
            int c = s * 4 + q, kk = c >> 3, cq = c & 7;
            int ra = wm * 64 + mt * 16 + (lane & 15);
            aflo[mt][s] = *(const half8*)&regB[kk * 8192 + ra * 64 + ((cq ^ (ra & 7)) * 8)];
        }
    __syncthreads();

    float ir[4][4];                                  // row reciprocals, once
#pragma unroll
    for (int mt = 0; mt < 4; ++mt) {
        float4 v4 = *(const float4*)&rowsum[i0 + wm * 64 + mt * 16 + q * 4];
        ir[mt][0] = 1.0f / v4.x; ir[mt][1] = 1.0f / v4.y;
        ir[mt][2] = 1.0f / v4.z; ir[mt][3] = 1.0f / v4.w;
    }

    unsigned long long rbv[4][4] = {};               // row argmax across stripe

    for (int jt = 0; jt < 5; ++jt) {
        stage_chunk(B2, regB, jp + jt * 128, 0, tid);
        __syncthreads();
        floatx4 acc[4][4] = {};
        compute_half<false>(regB, regA, aflo, lane, wm, wn, acc);
        __syncthreads();
        stage_chunk(B2, regB, jp + jt * 128, 1, tid);
        __syncthreads();
        compute_half<true>(regB, regA, aflo, lane, wm, wn, acc);

        int cb0 = jp + jt * 128 + wn * 64 + (lane & 15);
        float ic[4];
#pragma unroll
        for (int nt = 0; nt < 4; ++nt) ic[nt] = 1.0f / colsum[cb0 + nt * 16];

        unsigned long long colb[4] = {0ull, 0ull, 0ull, 0ull};
#pragma unroll
        for (int mt = 0; mt < 4; ++mt) {
            int rb0 = i0 + wm * 64 + mt * 16 + q * 4;
#pragma unroll
            for (int r = 0; r < 4; ++r) {
                int row = rb0 + r;
#pragma unroll
                for (int nt = 0; nt < 4; ++nt) {
                    float pv = __expf(20.0f * acc[mt][nt][r]) * ir[mt][r] * ic[nt];
                    P[row * N0 + cb0 + nt * 16] = pv;
                    unsigned long long pr = packvi(pv, cb0 + nt * 16);
                    if (pr > rbv[mt][r]) rbv[mt][r] = pr;
                    unsigned long long pc = packvi(pv, row);
                    if (pc > colb[nt]) colb[nt] = pc;
                }
            }
        }
#pragma unroll
        for (int nt = 0; nt < 4; ++nt) {
            unsigned long long o = __shfl_xor(colb[nt], 16);
            if (o > colb[nt]) colb[nt] = o;
            o = __shfl_xor(colb[nt], 32);
            if (o > colb[nt]) colb[nt] = o;
        }
        if (lane < 16)
#pragma unroll
            for (int nt = 0; nt < 4; ++nt)
                atomicMax(&colbest[cb0 + nt * 16], colb[nt]);
        __syncthreads();                             // regB reads + stores drain
    }
#pragma unroll
    for (int mt = 0; mt < 4; ++mt)
#pragma unroll
        for (int r = 0; r < 4; ++r) {
            unsigned long long v = rbv[mt][r];
#pragma unroll
            for (int s = 1; s < 16; s <<= 1) {
                unsigned long long o = __shfl_xor(v, s);
                if (o > v) v = o;
            }
            if ((lane & 15) == 0)
                atomicMax(&rowbest[i0 + wm * 64 + mt * 16 + q * 4 + r], v);
        }
}

// ---------------- K5: mutual-NN matching outputs -----------------------
__global__ __launch_bounds__(256) void kmatch(const unsigned long long* __restrict__ rowbest,
                                              const unsigned long long* __restrict__ colbest,
                                              float* __restrict__ out) {
    int i = blockIdx.x * 256 + threadIdx.x;      // 0..6399
    unsigned long long rb = rowbest[i];
    float conf = __uint_as_float((unsigned int)(rb >> 32));
    int jj = (int)(rb & 0xffffffffu);
    unsigned long long cb = colbest[jj];
    int i2 = (int)(cb & 0xffffffffu);
    bool valid = (i2 == i) && (conf > 0.2f);
    float vf = valid ? 1.0f : 0.0f;

    float* mk0   = out + 40960000;
    float* mk1   = out + 40972800;
    float* mconf = out + 40985600;
    float* vout  = out + 40992000;
    mk0[i * 2 + 0] = vf * (float)(i % WW);
    mk0[i * 2 + 1] = vf * (float)(i / WW);
    mk1[i * 2 + 0] = vf * (float)(jj % WW);
    mk1[i * 2 + 1] = vf * (float)(jj / WW);
    mconf[i] = valid ? conf : 0.0f;
    vout[i]  = vf;
}

extern "C" void kernel_launch(void* const* d_in, const int* in_sizes, int n_in,
                              void* d_out, int out_size, void* d_ws, size_t ws_size,
                              hipStream_t stream) {
    const float* f0 = (const float*)d_in[0];
    const float* f1 = (const float*)d_in[1];
    float* out = (float*)d_out;

    _Float16* A2 = (_Float16*)d_ws;                  // 6400x256 fp16
    _Float16* B2 = A2 + 6400 * 256;
    float* snorm  = (float*)(B2 + 6400 * 256);       // 25600 partial sumsq
    float* rowsum = snorm + 25600;
    float* colsum = rowsum + 6400;
    unsigned long long* rowbest = (unsigned long long*)(colsum + 6400);
    unsigned long long* colbest = rowbest + 6400;

    knorm<<<100, 256, 0, stream>>>(f0, f1, snorm,
                                   rowsum, colsum, rowbest, colbest);
    ktrans<<<dim3(200, 8, 2), 256, 0, stream>>>(f0, f1, snorm, A2, B2);
    kgemm1<<<dim3(50, 10), 256, 0, stream>>>(A2, B2, rowsum, colsum);
    kgemm2<<<dim3(50, 10), 256, 0, stream>>>(A2, B2, rowsum, colsum,
                                             out, rowbest, colbest);
    kmatch<<<25, 256, 0, stream>>>(rowbest, colbest, out);
}